// Round 1
// baseline (254.849 us; speedup 1.0000x reference)
//
#include <hip/hip_runtime.h>
#include <math.h>

#define HH 512
#define WW 512
#define NBC 24          // B*C = 8*3
#define TH 32
#define TW 32
#define RAD 4
#define TWO_PI 6.28318530717958647692f

__global__ __launch_bounds__(256) void egcl_fused(
    const float* __restrict__ outp,
    const float* __restrict__ tgtp,
    const int*   __restrict__ maskp,
    double*      __restrict__ acc)   // acc[0]=sum_w acc[1]=sum_mag acc[2]=sum_dir
{
    __shared__ float maskT[TH + 8][TW + 8];   // 40x40 mask tile (reflect pad)
    __shared__ float smh[TH][TW + 8];         // H-blurred, 32x40
    __shared__ float oT[TH + 2][TW + 2];      // 34x34 output tile (zero pad)
    __shared__ float tT[TH + 2][TW + 2];      // 34x34 target tile
    __shared__ float red[3][4];

    const int tid = threadIdx.x;
    const int y0 = blockIdx.y * TH;
    const int x0 = blockIdx.x * TW;
    const size_t plane = (size_t)blockIdx.z * (HH * WW);

    // Gaussian weights, f32 math to match jnp exactly
    float g[9];
    {
        float s = 0.f;
        #pragma unroll
        for (int j = 0; j < 9; ++j) {
            float x = (float)(j - RAD);
            g[j] = expf(-0.5f * x * x);
            s += g[j];
        }
        #pragma unroll
        for (int j = 0; j < 9; ++j) g[j] /= s;
    }

    // ---- load mask tile with symmetric (scipy 'reflect') padding ----
    for (int i = tid; i < (TH + 8) * (TW + 8); i += 256) {
        int r = i / (TW + 8), c = i % (TW + 8);
        int gy = y0 + r - RAD;
        if (gy < 0) gy = -gy - 1; else if (gy >= HH) gy = 2 * HH - 1 - gy;
        int gx = x0 + c - RAD;
        if (gx < 0) gx = -gx - 1; else if (gx >= WW) gx = 2 * WW - 1 - gx;
        maskT[r][c] = (float)maskp[plane + (size_t)gy * WW + gx];
    }
    // ---- load output/target tiles with zero padding ----
    for (int i = tid; i < (TH + 2) * (TW + 2); i += 256) {
        int r = i / (TW + 2), c = i % (TW + 2);
        int gy = y0 + r - 1, gx = x0 + c - 1;
        bool inb = (gy >= 0 && gy < HH && gx >= 0 && gx < WW);
        size_t idx = plane + (size_t)gy * WW + gx;
        oT[r][c] = inb ? outp[idx] : 0.f;
        tT[r][c] = inb ? tgtp[idx] : 0.f;
    }
    __syncthreads();

    // ---- blur along H into smh ----
    for (int i = tid; i < TH * (TW + 8); i += 256) {
        int r = i / (TW + 8), c = i % (TW + 8);
        float s = 0.f;
        #pragma unroll
        for (int j = 0; j < 9; ++j) s += g[j] * maskT[r + j][c];
        smh[r][c] = s;
    }
    __syncthreads();

    // ---- per-pixel compute: 4 pixels per thread ----
    float s_w = 0.f, s_mag = 0.f, s_dir = 0.f;
    const int pc = tid & 31;
    const int ty = tid >> 5;

    #pragma unroll
    for (int k = 0; k < 4; ++k) {
        int pr = ty + k * 8;

        // blur along W -> sm -> boundary weight
        float sm = 0.f;
        #pragma unroll
        for (int j = 0; j < 9; ++j) sm += g[j] * smh[pr][pc + j];
        sm = fminf(fmaxf(sm, 0.f), 1.f);
        float w = 1.f - fabsf(sm - 0.5f) * 2.f;
        w = fminf(fmaxf(w, 0.f), 1.f);

        // Sobel (cross-correlation, matches lax.conv)
        int r = pr + 1, c = pc + 1;
        float o00 = oT[r-1][c-1], o01 = oT[r-1][c], o02 = oT[r-1][c+1];
        float o10 = oT[r  ][c-1],                   o12 = oT[r  ][c+1];
        float o20 = oT[r+1][c-1], o21 = oT[r+1][c], o22 = oT[r+1][c+1];
        float gxo = (o02 - o00) + 2.f * (o12 - o10) + (o22 - o20);
        float gyo = (o20 + 2.f * o21 + o22) - (o00 + 2.f * o01 + o02);

        float t00 = tT[r-1][c-1], t01 = tT[r-1][c], t02 = tT[r-1][c+1];
        float t10 = tT[r  ][c-1],                   t12 = tT[r  ][c+1];
        float t20 = tT[r+1][c-1], t21 = tT[r+1][c], t22 = tT[r+1][c+1];
        float gxt = (t02 - t00) + 2.f * (t12 - t10) + (t22 - t20);
        float gyt = (t20 + 2.f * t21 + t22) - (t00 + 2.f * t01 + t02);

        float mago = sqrtf(gxo * gxo + gyo * gyo + 1e-8f);
        float magt = sqrtf(gxt * gxt + gyt * gyt + 1e-8f);
        float diro = atan2f(gyo, gxo);
        float dirt = atan2f(gyt, gxt);
        float dd = fabsf(diro - dirt);
        dd = fminf(dd, TWO_PI - dd);

        s_w   += w;
        s_mag += fabsf(mago * w - magt * w);
        s_dir += dd * w;
    }

    // ---- block reduction ----
    #pragma unroll
    for (int o = 32; o > 0; o >>= 1) {
        s_w   += __shfl_down(s_w,   o, 64);
        s_mag += __shfl_down(s_mag, o, 64);
        s_dir += __shfl_down(s_dir, o, 64);
    }
    const int wid = tid >> 6;
    if ((tid & 63) == 0) { red[0][wid] = s_w; red[1][wid] = s_mag; red[2][wid] = s_dir; }
    __syncthreads();
    if (tid == 0) {
        atomicAdd(&acc[0], (double)(red[0][0] + red[0][1] + red[0][2] + red[0][3]));
        atomicAdd(&acc[1], (double)(red[1][0] + red[1][1] + red[1][2] + red[1][3]));
        atomicAdd(&acc[2], (double)(red[2][0] + red[2][1] + red[2][2] + red[2][3]));
    }
}

__global__ void egcl_finalize(const double* __restrict__ acc, float* __restrict__ out)
{
    double Sw = acc[0], Smag = acc[1], Sdir = acc[2];
    const double N = (double)NBC * HH * WW;
    double mag_loss = Smag / N;
    if (Sw > 0.0) mag_loss = mag_loss / (Sw / N + 1e-8);
    double dir_loss = Sdir;
    if (Sw > 0.0) dir_loss = Sdir / (Sw + 1e-8);
    out[0] = (float)(mag_loss + dir_loss);
}

extern "C" void kernel_launch(void* const* d_in, const int* in_sizes, int n_in,
                              void* d_out, int out_size, void* d_ws, size_t ws_size,
                              hipStream_t stream)
{
    const float* outp = (const float*)d_in[0];
    const float* tgtp = (const float*)d_in[1];
    const int*   maskp = (const int*)d_in[2];
    double* acc = (double*)d_ws;

    hipMemsetAsync(acc, 0, 3 * sizeof(double), stream);

    dim3 grid(WW / TW, HH / TH, NBC);
    egcl_fused<<<grid, 256, 0, stream>>>(outp, tgtp, maskp, acc);
    egcl_finalize<<<1, 1, 0, stream>>>(acc, (float*)d_out);
}

// Round 2
// 65.861 us; speedup vs baseline: 3.8695x; 3.8695x over previous
//
#include <hip/hip_runtime.h>
#include <math.h>

#define HH 512
#define WW 512
#define NBC 24          // B*C = 8*3
#define TH 32
#define TW 32
#define RAD 4
#define NBLK ((HH / TH) * (WW / TW) * NBC)   // 16*16*24 = 6144

__global__ __launch_bounds__(256) void egcl_fused(
    const float* __restrict__ outp,
    const float* __restrict__ tgtp,
    const int*   __restrict__ maskp,
    float*       __restrict__ partials)  // [3][NBLK]: w, mag, dir
{
    __shared__ float maskT[TH + 8][TW + 8];   // 40x40 mask tile (reflect pad)
    __shared__ float smh[TH][TW + 8];         // H-blurred, 32x40
    __shared__ float oT[TH + 2][TW + 2];      // 34x34 output tile (zero pad)
    __shared__ float tT[TH + 2][TW + 2];      // 34x34 target tile
    __shared__ float red[3][4];

    const int tid = threadIdx.x;
    const int y0 = blockIdx.y * TH;
    const int x0 = blockIdx.x * TW;
    const size_t plane = (size_t)blockIdx.z * (HH * WW);

    // Gaussian weights, f32 math to match jnp exactly
    float g[9];
    {
        float s = 0.f;
        #pragma unroll
        for (int j = 0; j < 9; ++j) {
            float x = (float)(j - RAD);
            g[j] = expf(-0.5f * x * x);
            s += g[j];
        }
        #pragma unroll
        for (int j = 0; j < 9; ++j) g[j] /= s;
    }

    // ---- load mask tile with symmetric (scipy 'reflect') padding ----
    for (int i = tid; i < (TH + 8) * (TW + 8); i += 256) {
        int r = i / (TW + 8), c = i % (TW + 8);
        int gy = y0 + r - RAD;
        if (gy < 0) gy = -gy - 1; else if (gy >= HH) gy = 2 * HH - 1 - gy;
        int gx = x0 + c - RAD;
        if (gx < 0) gx = -gx - 1; else if (gx >= WW) gx = 2 * WW - 1 - gx;
        maskT[r][c] = (float)maskp[plane + (size_t)gy * WW + gx];
    }
    // ---- load output/target tiles with zero padding ----
    for (int i = tid; i < (TH + 2) * (TW + 2); i += 256) {
        int r = i / (TW + 2), c = i % (TW + 2);
        int gy = y0 + r - 1, gx = x0 + c - 1;
        bool inb = (gy >= 0 && gy < HH && gx >= 0 && gx < WW);
        size_t idx = plane + (size_t)gy * WW + gx;
        oT[r][c] = inb ? outp[idx] : 0.f;
        tT[r][c] = inb ? tgtp[idx] : 0.f;
    }
    __syncthreads();

    // ---- blur along H into smh ----
    for (int i = tid; i < TH * (TW + 8); i += 256) {
        int r = i / (TW + 8), c = i % (TW + 8);
        float s = 0.f;
        #pragma unroll
        for (int j = 0; j < 9; ++j) s += g[j] * maskT[r + j][c];
        smh[r][c] = s;
    }
    __syncthreads();

    // ---- per-pixel compute: 4 pixels per thread ----
    float s_w = 0.f, s_mag = 0.f, s_dir = 0.f;
    const int pc = tid & 31;
    const int ty = tid >> 5;

    #pragma unroll
    for (int k = 0; k < 4; ++k) {
        int pr = ty + k * 8;

        // blur along W -> sm -> boundary weight
        float sm = 0.f;
        #pragma unroll
        for (int j = 0; j < 9; ++j) sm += g[j] * smh[pr][pc + j];
        sm = fminf(fmaxf(sm, 0.f), 1.f);
        float w = 1.f - fabsf(sm - 0.5f) * 2.f;
        w = fminf(fmaxf(w, 0.f), 1.f);

        // Sobel (cross-correlation, matches lax.conv)
        int r = pr + 1, c = pc + 1;
        float o00 = oT[r-1][c-1], o01 = oT[r-1][c], o02 = oT[r-1][c+1];
        float o10 = oT[r  ][c-1],                   o12 = oT[r  ][c+1];
        float o20 = oT[r+1][c-1], o21 = oT[r+1][c], o22 = oT[r+1][c+1];
        float gxo = (o02 - o00) + 2.f * (o12 - o10) + (o22 - o20);
        float gyo = (o20 + 2.f * o21 + o22) - (o00 + 2.f * o01 + o02);

        float t00 = tT[r-1][c-1], t01 = tT[r-1][c], t02 = tT[r-1][c+1];
        float t10 = tT[r  ][c-1],                   t12 = tT[r  ][c+1];
        float t20 = tT[r+1][c-1], t21 = tT[r+1][c], t22 = tT[r+1][c+1];
        float gxt = (t02 - t00) + 2.f * (t12 - t10) + (t22 - t20);
        float gyt = (t20 + 2.f * t21 + t22) - (t00 + 2.f * t01 + t02);

        float mago = sqrtf(gxo * gxo + gyo * gyo + 1e-8f);
        float magt = sqrtf(gxt * gxt + gyt * gyt + 1e-8f);

        // circular direction distance via single atan2:
        // min(|diro-dirt|, 2pi-|diro-dirt|) == |atan2(cross, dot)|
        float cross = gyo * gxt - gxo * gyt;
        float dotp  = gxo * gxt + gyo * gyt;
        float dd = fabsf(atan2f(cross, dotp));

        s_w   += w;
        s_mag += fabsf(mago * w - magt * w);
        s_dir += dd * w;
    }

    // ---- block reduction (wave shfl, then LDS across 4 waves) ----
    #pragma unroll
    for (int o = 32; o > 0; o >>= 1) {
        s_w   += __shfl_down(s_w,   o, 64);
        s_mag += __shfl_down(s_mag, o, 64);
        s_dir += __shfl_down(s_dir, o, 64);
    }
    const int wid = tid >> 6;
    if ((tid & 63) == 0) { red[0][wid] = s_w; red[1][wid] = s_mag; red[2][wid] = s_dir; }
    __syncthreads();
    if (tid == 0) {
        const int bid = ((int)blockIdx.z * gridDim.y + blockIdx.y) * gridDim.x + blockIdx.x;
        partials[bid]            = red[0][0] + red[0][1] + red[0][2] + red[0][3];
        partials[NBLK + bid]     = red[1][0] + red[1][1] + red[1][2] + red[1][3];
        partials[2 * NBLK + bid] = red[2][0] + red[2][1] + red[2][2] + red[2][3];
    }
}

__global__ __launch_bounds__(256) void egcl_finalize(
    const float* __restrict__ partials, float* __restrict__ out)
{
    __shared__ double red[3][4];
    const int tid = threadIdx.x;
    double s0 = 0.0, s1 = 0.0, s2 = 0.0;
    for (int i = tid; i < NBLK; i += 256) {
        s0 += (double)partials[i];
        s1 += (double)partials[NBLK + i];
        s2 += (double)partials[2 * NBLK + i];
    }
    #pragma unroll
    for (int o = 32; o > 0; o >>= 1) {
        s0 += __shfl_down(s0, o, 64);
        s1 += __shfl_down(s1, o, 64);
        s2 += __shfl_down(s2, o, 64);
    }
    const int wid = tid >> 6;
    if ((tid & 63) == 0) { red[0][wid] = s0; red[1][wid] = s1; red[2][wid] = s2; }
    __syncthreads();
    if (tid == 0) {
        double Sw   = red[0][0] + red[0][1] + red[0][2] + red[0][3];
        double Smag = red[1][0] + red[1][1] + red[1][2] + red[1][3];
        double Sdir = red[2][0] + red[2][1] + red[2][2] + red[2][3];
        const double N = (double)NBC * HH * WW;
        double mag_loss = Smag / N;
        if (Sw > 0.0) mag_loss = mag_loss / (Sw / N + 1e-8);
        double dir_loss = Sdir;
        if (Sw > 0.0) dir_loss = Sdir / (Sw + 1e-8);
        out[0] = (float)(mag_loss + dir_loss);
    }
}

extern "C" void kernel_launch(void* const* d_in, const int* in_sizes, int n_in,
                              void* d_out, int out_size, void* d_ws, size_t ws_size,
                              hipStream_t stream)
{
    const float* outp = (const float*)d_in[0];
    const float* tgtp = (const float*)d_in[1];
    const int*   maskp = (const int*)d_in[2];
    float* partials = (float*)d_ws;

    dim3 grid(WW / TW, HH / TH, NBC);
    egcl_fused<<<grid, 256, 0, stream>>>(outp, tgtp, maskp, partials);
    egcl_finalize<<<1, 256, 0, stream>>>(partials, (float*)d_out);
}

// Round 4
// 61.082 us; speedup vs baseline: 4.1722x; 1.0782x over previous
//
#include <hip/hip_runtime.h>
#include <math.h>

#define HH 512
#define WW 512
#define NBC 24          // B*C = 8*3
#define TH 32
#define TW 32
#define RAD 4
#define NBLK ((HH / TH) * (WW / TW) * NBC)   // 16*16*24 = 6144
#define PI_F 3.14159265358979323846f

// Gaussian taps: exp(-0.5*x^2)/sum, x=-4..4, computed in double, rounded to f32.
// Matches jnp's f32 computation to <=1 ulp per tap.
__device__ __constant__ float GW[9] = {
    1.3383023e-04f, 4.4318484e-03f, 5.3990968e-02f, 2.4197073e-01f,
    3.9894228e-01f, 2.4197073e-01f, 5.3990968e-02f, 4.4318484e-03f,
    1.3383023e-04f
};

// |atan2(y,x)| in [0,pi], branchless, ~3e-7 max error, NaN-free.
__device__ __forceinline__ float abs_atan2_fast(float y, float x)
{
    float ax = fabsf(x), ay = fabsf(y);
    float mx = fmaxf(ax, ay), mn = fminf(ax, ay);
    float t = mn * __builtin_amdgcn_rcpf(fmaxf(mx, 1e-30f));
    float s = t * t;
    float r = -0.01172120f;
    r = fmaf(r, s, 0.05265332f);
    r = fmaf(r, s, -0.11643287f);
    r = fmaf(r, s, 0.19354346f);
    r = fmaf(r, s, -0.33262347f);
    r = fmaf(r, s, 0.99997726f);
    r = r * t;                                  // atan(mn/mx) in [0, pi/4]
    r = (ay > ax) ? (0.5f * PI_F - r) : r;      // undo octant swap
    r = (x < 0.f) ? (PI_F - r) : r;             // quadrant
    return r;                                   // == |atan2(y,x)|
}

__global__ __launch_bounds__(256) void egcl_fused(
    const float* __restrict__ outp,
    const float* __restrict__ tgtp,
    const int*   __restrict__ maskp,
    float*       __restrict__ partials)  // [3][NBLK]: w, mag, dir
{
    __shared__ float maskT[TH + 8][TW + 8];   // 40x40 mask tile (reflect pad)
    __shared__ float smh[TH][TW + 8];         // H-blurred, 32x40
    __shared__ float oT[TH + 2][TW + 2];      // 34x34 output tile (zero pad)
    __shared__ float tT[TH + 2][TW + 2];      // 34x34 target tile
    __shared__ float red[3][4];

    const int tid = threadIdx.x;
    const int y0 = blockIdx.y * TH;
    const int x0 = blockIdx.x * TW;
    const size_t plane = (size_t)blockIdx.z * (HH * WW);

    // ---- load mask tile with symmetric (scipy 'reflect') padding ----
    for (int i = tid; i < (TH + 8) * (TW + 8); i += 256) {
        int r = i / (TW + 8), c = i % (TW + 8);
        int gy = y0 + r - RAD;
        if (gy < 0) gy = -gy - 1; else if (gy >= HH) gy = 2 * HH - 1 - gy;
        int gx = x0 + c - RAD;
        if (gx < 0) gx = -gx - 1; else if (gx >= WW) gx = 2 * WW - 1 - gx;
        maskT[r][c] = (float)maskp[plane + (size_t)gy * WW + gx];
    }
    // ---- load output/target tiles with zero padding ----
    for (int i = tid; i < (TH + 2) * (TW + 2); i += 256) {
        int r = i / (TW + 2), c = i % (TW + 2);
        int gy = y0 + r - 1, gx = x0 + c - 1;
        bool inb = (gy >= 0 && gy < HH && gx >= 0 && gx < WW);
        size_t idx = plane + (size_t)gy * WW + gx;
        oT[r][c] = inb ? outp[idx] : 0.f;
        tT[r][c] = inb ? tgtp[idx] : 0.f;
    }
    __syncthreads();

    // ---- blur along H into smh (exactly 5 iters: 32*40 = 5*256) ----
    #pragma unroll
    for (int i = tid; i < TH * (TW + 8); i += 256) {
        int r = i / (TW + 8), c = i % (TW + 8);
        float s = 0.f;
        #pragma unroll
        for (int j = 0; j < 9; ++j) s = fmaf(GW[j], maskT[r + j][c], s);
        smh[r][c] = s;
    }
    __syncthreads();

    // ---- per-pixel compute: 4 pixels per thread ----
    float s_w = 0.f, s_mag = 0.f, s_dir = 0.f;
    const int pc = tid & 31;
    const int ty = tid >> 5;

    #pragma unroll
    for (int k = 0; k < 4; ++k) {
        int pr = ty + k * 8;

        // blur along W -> sm -> boundary weight
        float sm = 0.f;
        #pragma unroll
        for (int j = 0; j < 9; ++j) sm = fmaf(GW[j], smh[pr][pc + j], sm);
        sm = fminf(fmaxf(sm, 0.f), 1.f);
        float w = 1.f - fabsf(sm - 0.5f) * 2.f;
        w = fminf(fmaxf(w, 0.f), 1.f);

        // Sobel (cross-correlation, matches lax.conv)
        int r = pr + 1, c = pc + 1;
        float o00 = oT[r-1][c-1], o01 = oT[r-1][c], o02 = oT[r-1][c+1];
        float o10 = oT[r  ][c-1],                   o12 = oT[r  ][c+1];
        float o20 = oT[r+1][c-1], o21 = oT[r+1][c], o22 = oT[r+1][c+1];
        float gxo = (o02 - o00) + 2.f * (o12 - o10) + (o22 - o20);
        float gyo = (o20 + 2.f * o21 + o22) - (o00 + 2.f * o01 + o02);

        float t00 = tT[r-1][c-1], t01 = tT[r-1][c], t02 = tT[r-1][c+1];
        float t10 = tT[r  ][c-1],                   t12 = tT[r  ][c+1];
        float t20 = tT[r+1][c-1], t21 = tT[r+1][c], t22 = tT[r+1][c+1];
        float gxt = (t02 - t00) + 2.f * (t12 - t10) + (t22 - t20);
        float gyt = (t20 + 2.f * t21 + t22) - (t00 + 2.f * t01 + t02);

        float mago = __builtin_amdgcn_sqrtf(fmaf(gxo, gxo, fmaf(gyo, gyo, 1e-8f)));
        float magt = __builtin_amdgcn_sqrtf(fmaf(gxt, gxt, fmaf(gyt, gyt, 1e-8f)));

        // circular direction distance via single fast |atan2|:
        float cross = gyo * gxt - gxo * gyt;
        float dotp  = fmaf(gxo, gxt, gyo * gyt);
        float dd = abs_atan2_fast(cross, dotp);

        s_w   += w;
        s_mag += w * fabsf(mago - magt);
        s_dir += dd * w;
    }

    // ---- block reduction (wave shfl, then LDS across 4 waves) ----
    #pragma unroll
    for (int o = 32; o > 0; o >>= 1) {
        s_w   += __shfl_down(s_w,   o, 64);
        s_mag += __shfl_down(s_mag, o, 64);
        s_dir += __shfl_down(s_dir, o, 64);
    }
    const int wid = tid >> 6;
    if ((tid & 63) == 0) { red[0][wid] = s_w; red[1][wid] = s_mag; red[2][wid] = s_dir; }
    __syncthreads();
    if (tid == 0) {
        const int bid = ((int)blockIdx.z * gridDim.y + blockIdx.y) * gridDim.x + blockIdx.x;
        partials[bid]            = red[0][0] + red[0][1] + red[0][2] + red[0][3];
        partials[NBLK + bid]     = red[1][0] + red[1][1] + red[1][2] + red[1][3];
        partials[2 * NBLK + bid] = red[2][0] + red[2][1] + red[2][2] + red[2][3];
    }
}

__global__ __launch_bounds__(256) void egcl_finalize(
    const float* __restrict__ partials, float* __restrict__ out)
{
    __shared__ double red[3][4];
    const int tid = threadIdx.x;
    double s0 = 0.0, s1 = 0.0, s2 = 0.0;
    for (int i = tid; i < NBLK; i += 256) {
        s0 += (double)partials[i];
        s1 += (double)partials[NBLK + i];
        s2 += (double)partials[2 * NBLK + i];
    }
    #pragma unroll
    for (int o = 32; o > 0; o >>= 1) {
        s0 += __shfl_down(s0, o, 64);
        s1 += __shfl_down(s1, o, 64);
        s2 += __shfl_down(s2, o, 64);
    }
    const int wid = tid >> 6;
    if ((tid & 63) == 0) { red[0][wid] = s0; red[1][wid] = s1; red[2][wid] = s2; }
    __syncthreads();
    if (tid == 0) {
        double Sw   = red[0][0] + red[0][1] + red[0][2] + red[0][3];
        double Smag = red[1][0] + red[1][1] + red[1][2] + red[1][3];
        double Sdir = red[2][0] + red[2][1] + red[2][2] + red[2][3];
        const double N = (double)NBC * HH * WW;
        double mag_loss = Smag / N;
        if (Sw > 0.0) mag_loss = mag_loss / (Sw / N + 1e-8);
        double dir_loss = Sdir;
        if (Sw > 0.0) dir_loss = Sdir / (Sw + 1e-8);
        out[0] = (float)(mag_loss + dir_loss);
    }
}

extern "C" void kernel_launch(void* const* d_in, const int* in_sizes, int n_in,
                              void* d_out, int out_size, void* d_ws, size_t ws_size,
                              hipStream_t stream)
{
    const float* outp = (const float*)d_in[0];
    const float* tgtp = (const float*)d_in[1];
    const int*   maskp = (const int*)d_in[2];
    float* partials = (float*)d_ws;

    dim3 grid(WW / TW, HH / TH, NBC);
    egcl_fused<<<grid, 256, 0, stream>>>(outp, tgtp, maskp, partials);
    egcl_finalize<<<1, 256, 0, stream>>>(partials, (float*)d_out);
}

// Round 5
// 57.598 us; speedup vs baseline: 4.4246x; 1.0605x over previous
//
#include <hip/hip_runtime.h>
#include <math.h>

#define HH 512
#define WW 512
#define NBC 24          // B*C = 8*3
#define TH 32
#define TW 32
#define RAD 4
#define NBLK ((HH / TH) * (WW / TW) * NBC)   // 6144
#define PI_F 3.14159265358979323846f

// Gaussian taps: exp(-0.5*x^2)/sum, x=-4..4 (double-computed, f32-rounded;
// <=1 ulp vs jnp's f32 path).
__device__ __constant__ float GW[9] = {
    1.3383023e-04f, 4.4318484e-03f, 5.3990968e-02f, 2.4197073e-01f,
    3.9894228e-01f, 2.4197073e-01f, 5.3990968e-02f, 4.4318484e-03f,
    1.3383023e-04f
};

// |atan2(y,x)| in [0,pi], branchless, ~3e-7 max error, NaN-free.
__device__ __forceinline__ float abs_atan2_fast(float y, float x)
{
    float ax = fabsf(x), ay = fabsf(y);
    float mx = fmaxf(ax, ay), mn = fminf(ax, ay);
    float t = mn * __builtin_amdgcn_rcpf(fmaxf(mx, 1e-30f));
    float s = t * t;
    float r = -0.01172120f;
    r = fmaf(r, s, 0.05265332f);
    r = fmaf(r, s, -0.11643287f);
    r = fmaf(r, s, 0.19354346f);
    r = fmaf(r, s, -0.33262347f);
    r = fmaf(r, s, 0.99997726f);
    r = r * t;                                  // atan(mn/mx) in [0, pi/4]
    r = (ay > ax) ? (0.5f * PI_F - r) : r;      // undo octant swap
    r = (x < 0.f) ? (PI_F - r) : r;             // quadrant
    return r;
}

__global__ __launch_bounds__(256) void egcl_fused(
    const float* __restrict__ outp,
    const float* __restrict__ tgtp,
    const int*   __restrict__ maskp,
    float*       __restrict__ partials)  // [3][NBLK]: w, mag, dir
{
    // row strides chosen as multiples of 4 floats so float4/float2 LDS
    // accesses are 16/8-B aligned.
    __shared__ __align__(16) float maskT[TH + 8][TW + 8];  // 40x40
    __shared__ __align__(16) float smh[TH][TW + 8];        // 32x40 H-blurred
    __shared__ __align__(16) float oT[TH + 2][TW + 4];     // 34 rows x 36 (cols 0..33 valid)
    __shared__ __align__(16) float tT[TH + 2][TW + 4];
    __shared__ float red[3][4];

    const int tid = threadIdx.x;
    const int y0 = blockIdx.y * TH;
    const int x0 = blockIdx.x * TW;
    const size_t plane = (size_t)blockIdx.z * (HH * WW);

    // ---- stage mask tile (symmetric/reflect pad), scalar ----
    for (int i = tid; i < (TH + 8) * (TW + 8); i += 256) {
        int r = i / (TW + 8), c = i % (TW + 8);
        int gy = y0 + r - RAD;
        if (gy < 0) gy = -gy - 1; else if (gy >= HH) gy = 2 * HH - 1 - gy;
        int gx = x0 + c - RAD;
        if (gx < 0) gx = -gx - 1; else if (gx >= WW) gx = 2 * WW - 1 - gx;
        maskT[r][c] = (float)maskp[plane + (size_t)gy * WW + gx];
    }
    // ---- stage output/target tiles (zero pad), scalar ----
    for (int i = tid; i < (TH + 2) * (TW + 2); i += 256) {
        int r = i / (TW + 2), c = i % (TW + 2);
        int gy = y0 + r - 1, gx = x0 + c - 1;
        bool inb = (gy >= 0 && gy < HH && gx >= 0 && gx < WW);
        size_t idx = plane + (size_t)gy * WW + gx;
        oT[r][c] = inb ? outp[idx] : 0.f;
        tT[r][c] = inb ? tgtp[idx] : 0.f;
    }
    __syncthreads();

    // ---- H-blur, vectorized: 32 rows x 10 col-groups of 4 = 320 groups ----
    for (int i = tid; i < TH * 10; i += 256) {
        int r = i / 10, cg = (i % 10) * 4;
        float4 acc = make_float4(0.f, 0.f, 0.f, 0.f);
        #pragma unroll
        for (int j = 0; j < 9; ++j) {
            float4 m = *(const float4*)&maskT[r + j][cg];
            acc.x = fmaf(GW[j], m.x, acc.x);
            acc.y = fmaf(GW[j], m.y, acc.y);
            acc.z = fmaf(GW[j], m.z, acc.z);
            acc.w = fmaf(GW[j], m.w, acc.w);
        }
        *(float4*)&smh[r][cg] = acc;
    }
    __syncthreads();

    // ---- per-pixel compute: each thread owns 4 CONSECUTIVE cols of one row ----
    const int r  = tid >> 3;          // 0..31
    const int c4 = (tid & 7) << 2;    // 0,4,...,28

    // W-blur window: smh[r][c4 .. c4+11], 3x ds_read_b128
    float win[12];
    *(float4*)&win[0] = *(const float4*)&smh[r][c4];
    *(float4*)&win[4] = *(const float4*)&smh[r][c4 + 4];
    *(float4*)&win[8] = *(const float4*)&smh[r][c4 + 8];

    float wgt[4];
    #pragma unroll
    for (int i = 0; i < 4; ++i) {
        float sm = 0.f;
        #pragma unroll
        for (int j = 0; j < 9; ++j) sm = fmaf(GW[j], win[i + j], sm);
        sm = fminf(fmaxf(sm, 0.f), 1.f);
        float w = 1.f - fabsf(sm - 0.5f) * 2.f;
        wgt[i] = fminf(fmaxf(w, 0.f), 1.f);
    }

    // Sobel windows: padded rows r..r+2, cols c4..c4+5 (b128 + b64 per row)
    float ao[6], bo[6], co[6], at[6], bt[6], ct[6];
    *(float4*)&ao[0] = *(const float4*)&oT[r    ][c4];
    *(float2*)&ao[4] = *(const float2*)&oT[r    ][c4 + 4];
    *(float4*)&bo[0] = *(const float4*)&oT[r + 1][c4];
    *(float2*)&bo[4] = *(const float2*)&oT[r + 1][c4 + 4];
    *(float4*)&co[0] = *(const float4*)&oT[r + 2][c4];
    *(float2*)&co[4] = *(const float2*)&oT[r + 2][c4 + 4];
    *(float4*)&at[0] = *(const float4*)&tT[r    ][c4];
    *(float2*)&at[4] = *(const float2*)&tT[r    ][c4 + 4];
    *(float4*)&bt[0] = *(const float4*)&tT[r + 1][c4];
    *(float2*)&bt[4] = *(const float2*)&tT[r + 1][c4 + 4];
    *(float4*)&ct[0] = *(const float4*)&tT[r + 2][c4];
    *(float2*)&ct[4] = *(const float2*)&tT[r + 2][c4 + 4];

    // separable Sobel: gx[i] = t[i+2]-t[i] with t=a+2b+c; gy[i] = u[i]+2u[i+1]+u[i+2] with u=c-a
    float to_[6], uo[6], tt_[6], ut[6];
    #pragma unroll
    for (int j = 0; j < 6; ++j) {
        to_[j] = fmaf(2.f, bo[j], ao[j] + co[j]);
        uo[j]  = co[j] - ao[j];
        tt_[j] = fmaf(2.f, bt[j], at[j] + ct[j]);
        ut[j]  = ct[j] - at[j];
    }

    float s_w = 0.f, s_mag = 0.f, s_dir = 0.f;
    #pragma unroll
    for (int i = 0; i < 4; ++i) {
        float gxo = to_[i + 2] - to_[i];
        float gyo = fmaf(2.f, uo[i + 1], uo[i] + uo[i + 2]);
        float gxt = tt_[i + 2] - tt_[i];
        float gyt = fmaf(2.f, ut[i + 1], ut[i] + ut[i + 2]);

        float mago = __builtin_amdgcn_sqrtf(fmaf(gxo, gxo, fmaf(gyo, gyo, 1e-8f)));
        float magt = __builtin_amdgcn_sqrtf(fmaf(gxt, gxt, fmaf(gyt, gyt, 1e-8f)));

        float cross = gyo * gxt - gxo * gyt;
        float dotp  = fmaf(gxo, gxt, gyo * gyt);
        float dd = abs_atan2_fast(cross, dotp);

        s_w   += wgt[i];
        s_mag += wgt[i] * fabsf(mago - magt);
        s_dir += dd * wgt[i];
    }

    // ---- block reduction ----
    #pragma unroll
    for (int o = 32; o > 0; o >>= 1) {
        s_w   += __shfl_down(s_w,   o, 64);
        s_mag += __shfl_down(s_mag, o, 64);
        s_dir += __shfl_down(s_dir, o, 64);
    }
    const int wid = tid >> 6;
    if ((tid & 63) == 0) { red[0][wid] = s_w; red[1][wid] = s_mag; red[2][wid] = s_dir; }
    __syncthreads();
    if (tid == 0) {
        const int bid = ((int)blockIdx.z * gridDim.y + blockIdx.y) * gridDim.x + blockIdx.x;
        partials[bid]            = red[0][0] + red[0][1] + red[0][2] + red[0][3];
        partials[NBLK + bid]     = red[1][0] + red[1][1] + red[1][2] + red[1][3];
        partials[2 * NBLK + bid] = red[2][0] + red[2][1] + red[2][2] + red[2][3];
    }
}

__global__ __launch_bounds__(256) void egcl_finalize(
    const float* __restrict__ partials, float* __restrict__ out)
{
    __shared__ double red[3][4];
    const int tid = threadIdx.x;
    double s0 = 0.0, s1 = 0.0, s2 = 0.0;
    const float4* p0 = (const float4*)partials;
    const float4* p1 = (const float4*)(partials + NBLK);
    const float4* p2 = (const float4*)(partials + 2 * NBLK);
    for (int i = tid; i < NBLK / 4; i += 256) {
        float4 a = p0[i], b = p1[i], c = p2[i];
        s0 += (double)a.x + (double)a.y + (double)a.z + (double)a.w;
        s1 += (double)b.x + (double)b.y + (double)b.z + (double)b.w;
        s2 += (double)c.x + (double)c.y + (double)c.z + (double)c.w;
    }
    #pragma unroll
    for (int o = 32; o > 0; o >>= 1) {
        s0 += __shfl_down(s0, o, 64);
        s1 += __shfl_down(s1, o, 64);
        s2 += __shfl_down(s2, o, 64);
    }
    const int wid = tid >> 6;
    if ((tid & 63) == 0) { red[0][wid] = s0; red[1][wid] = s1; red[2][wid] = s2; }
    __syncthreads();
    if (tid == 0) {
        double Sw   = red[0][0] + red[0][1] + red[0][2] + red[0][3];
        double Smag = red[1][0] + red[1][1] + red[1][2] + red[1][3];
        double Sdir = red[2][0] + red[2][1] + red[2][2] + red[2][3];
        const double N = (double)NBC * HH * WW;
        double mag_loss = Smag / N;
        if (Sw > 0.0) mag_loss = mag_loss / (Sw / N + 1e-8);
        double dir_loss = Sdir;
        if (Sw > 0.0) dir_loss = Sdir / (Sw + 1e-8);
        out[0] = (float)(mag_loss + dir_loss);
    }
}

extern "C" void kernel_launch(void* const* d_in, const int* in_sizes, int n_in,
                              void* d_out, int out_size, void* d_ws, size_t ws_size,
                              hipStream_t stream)
{
    const float* outp = (const float*)d_in[0];
    const float* tgtp = (const float*)d_in[1];
    const int*   maskp = (const int*)d_in[2];
    float* partials = (float*)d_ws;

    dim3 grid(WW / TW, HH / TH, NBC);
    egcl_fused<<<grid, 256, 0, stream>>>(outp, tgtp, maskp, partials);
    egcl_finalize<<<1, 256, 0, stream>>>(partials, (float*)d_out);
}

// Round 6
// 46.587 us; speedup vs baseline: 5.4704x; 1.2363x over previous
//
#include <hip/hip_runtime.h>
#include <math.h>

#define HH 512
#define WW 512
#define NBC 24          // B*C = 8*3
#define TH 32
#define TW 32
#define RAD 4
#define NBLK ((HH / TH) * (WW / TW) * NBC)   // 6144
#define PI_F 3.14159265358979323846f
#define SMW 36          // LDS row stride (floats) for all tiles: (4r+c)%32 tiles banks cleanly

// Gaussian taps: exp(-0.5*x^2)/sum, x=-4..4 (double-computed, f32-rounded;
// <=1 ulp vs jnp's f32 path).
__device__ __constant__ float GW[9] = {
    1.3383023e-04f, 4.4318484e-03f, 5.3990968e-02f, 2.4197073e-01f,
    3.9894228e-01f, 2.4197073e-01f, 5.3990968e-02f, 4.4318484e-03f,
    1.3383023e-04f
};

// |atan2(y,x)| in [0,pi], branchless, ~3e-7 max error, NaN-free.
__device__ __forceinline__ float abs_atan2_fast(float y, float x)
{
    float ax = fabsf(x), ay = fabsf(y);
    float mx = fmaxf(ax, ay), mn = fminf(ax, ay);
    float t = mn * __builtin_amdgcn_rcpf(fmaxf(mx, 1e-30f));
    float s = t * t;
    float r = -0.01172120f;
    r = fmaf(r, s, 0.05265332f);
    r = fmaf(r, s, -0.11643287f);
    r = fmaf(r, s, 0.19354346f);
    r = fmaf(r, s, -0.33262347f);
    r = fmaf(r, s, 0.99997726f);
    r = r * t;                                  // atan(mn/mx) in [0, pi/4]
    r = (ay > ax) ? (0.5f * PI_F - r) : r;      // undo octant swap
    r = (x < 0.f) ? (PI_F - r) : r;             // quadrant
    return r;
}

__global__ __launch_bounds__(256) void egcl_fused(
    const float* __restrict__ outp,
    const float* __restrict__ tgtp,
    const int*   __restrict__ maskp,
    float*       __restrict__ partials)  // [3][NBLK]: w, mag, dir
{
    __shared__ __align__(16) float smh[TH + 8][SMW];  // 40 rows, H-blurred mask (cols 0..31)
    __shared__ __align__(16) float oT[TH + 2][SMW];   // 34 rows, cols 0..35 = image x0-1..x0+34
    __shared__ __align__(16) float tT[TH + 2][SMW];
    __shared__ float red[3][4];

    const int tid = threadIdx.x;
    const int y0 = blockIdx.y * TH;
    const int x0 = blockIdx.x * TW;
    const size_t plane = (size_t)blockIdx.z * (HH * WW);
    const bool xedge = (x0 == 0) || (x0 == WW - TW);

    // ---- mask: global -> registers -> H-blur -> smh (no raw-mask LDS) ----
    // 40 rows x 8 col-groups of 4 = 320 tasks
    for (int i = tid; i < 40 * 8; i += 256) {
        int r = i >> 3, cg = (i & 7) << 2;
        int gy = y0 + r - RAD;
        gy = (gy < 0) ? (-gy - 1) : ((gy >= HH) ? (2 * HH - 1 - gy) : gy);
        const int* mrow = maskp + plane + (size_t)gy * WW;
        float win[12];
        if (!xedge) {
            int4 a = *(const int4*)&mrow[x0 + cg - 4];
            int4 b = *(const int4*)&mrow[x0 + cg];
            int4 c = *(const int4*)&mrow[x0 + cg + 4];
            win[0] = (float)a.x; win[1]  = (float)a.y; win[2]  = (float)a.z; win[3]  = (float)a.w;
            win[4] = (float)b.x; win[5]  = (float)b.y; win[6]  = (float)b.z; win[7]  = (float)b.w;
            win[8] = (float)c.x; win[9]  = (float)c.y; win[10] = (float)c.z; win[11] = (float)c.w;
        } else {
            #pragma unroll
            for (int k = 0; k < 12; ++k) {
                int gx = x0 + cg - 4 + k;
                gx = (gx < 0) ? (-gx - 1) : ((gx >= WW) ? (2 * WW - 1 - gx) : gx);
                win[k] = (float)mrow[gx];
            }
        }
        float s0 = 0.f, s1 = 0.f, s2 = 0.f, s3 = 0.f;
        #pragma unroll
        for (int j = 0; j < 9; ++j) {
            float gw = GW[j];
            s0 = fmaf(gw, win[j],     s0);
            s1 = fmaf(gw, win[j + 1], s1);
            s2 = fmaf(gw, win[j + 2], s2);
            s3 = fmaf(gw, win[j + 3], s3);
        }
        *(float4*)&smh[r][cg] = make_float4(s0, s1, s2, s3);
    }

    // ---- o/t tiles: vectorized staging. 34 rows x 9 groups of 4 = 306 tasks ----
    for (int i = tid; i < 34 * 9; i += 256) {
        int r = i / 9, g = i % 9;
        int gy = y0 + r - 1;
        bool rowin = (gy >= 0) && (gy < HH);
        float4 vo = make_float4(0.f, 0.f, 0.f, 0.f);
        float4 vt = vo;
        if (rowin) {
            const size_t rowbase = plane + (size_t)gy * WW;
            if (!xedge) {
                vo = *(const float4*)&outp[rowbase + (x0 - 1 + 4 * g)];
                vt = *(const float4*)&tgtp[rowbase + (x0 - 1 + 4 * g)];
            } else {
                float a[4], b[4];
                #pragma unroll
                for (int k = 0; k < 4; ++k) {
                    int gx = x0 - 1 + 4 * g + k;
                    bool in = (gx >= 0) && (gx < WW);
                    size_t idx = rowbase + (in ? gx : 0);
                    a[k] = in ? outp[idx] : 0.f;
                    b[k] = in ? tgtp[idx] : 0.f;
                }
                vo = make_float4(a[0], a[1], a[2], a[3]);
                vt = make_float4(b[0], b[1], b[2], b[3]);
            }
        }
        *(float4*)&oT[r][4 * g] = vo;
        *(float4*)&tT[r][4 * g] = vt;
    }
    __syncthreads();   // the ONLY barrier

    // ---- compute: thread owns 4 consecutive cols of one row ----
    const int r  = tid >> 3;          // 0..31
    const int c4 = (tid & 7) << 2;    // 0,4,...,28

    // V-blur: wgt for 4 pixels
    float a0 = 0.f, a1 = 0.f, a2 = 0.f, a3 = 0.f;
    #pragma unroll
    for (int j = 0; j < 9; ++j) {
        float4 m = *(const float4*)&smh[r + j][c4];
        float gw = GW[j];
        a0 = fmaf(gw, m.x, a0);
        a1 = fmaf(gw, m.y, a1);
        a2 = fmaf(gw, m.z, a2);
        a3 = fmaf(gw, m.w, a3);
    }
    float wgt[4];
    {
        float smv[4] = {a0, a1, a2, a3};
        #pragma unroll
        for (int i = 0; i < 4; ++i) {
            float sm = fminf(fmaxf(smv[i], 0.f), 1.f);
            float w = 1.f - fabsf(sm - 0.5f) * 2.f;
            wgt[i] = fminf(fmaxf(w, 0.f), 1.f);
        }
    }

    // Sobel windows: rows r..r+2, LDS cols c4..c4+5 (image cols x0+c4-1..x0+c4+4)
    float ao[6], bo[6], co[6], at[6], bt[6], ct[6];
    *(float4*)&ao[0] = *(const float4*)&oT[r    ][c4];
    *(float2*)&ao[4] = *(const float2*)&oT[r    ][c4 + 4];
    *(float4*)&bo[0] = *(const float4*)&oT[r + 1][c4];
    *(float2*)&bo[4] = *(const float2*)&oT[r + 1][c4 + 4];
    *(float4*)&co[0] = *(const float4*)&oT[r + 2][c4];
    *(float2*)&co[4] = *(const float2*)&oT[r + 2][c4 + 4];
    *(float4*)&at[0] = *(const float4*)&tT[r    ][c4];
    *(float2*)&at[4] = *(const float2*)&tT[r    ][c4 + 4];
    *(float4*)&bt[0] = *(const float4*)&tT[r + 1][c4];
    *(float2*)&bt[4] = *(const float2*)&tT[r + 1][c4 + 4];
    *(float4*)&ct[0] = *(const float4*)&tT[r + 2][c4];
    *(float2*)&ct[4] = *(const float2*)&tT[r + 2][c4 + 4];

    // separable Sobel: gx[i] = t[i+2]-t[i] with t=a+2b+c; gy[i] = u[i]+2u[i+1]+u[i+2] with u=c-a
    float to_[6], uo[6], tt_[6], ut[6];
    #pragma unroll
    for (int j = 0; j < 6; ++j) {
        to_[j] = fmaf(2.f, bo[j], ao[j] + co[j]);
        uo[j]  = co[j] - ao[j];
        tt_[j] = fmaf(2.f, bt[j], at[j] + ct[j]);
        ut[j]  = ct[j] - at[j];
    }

    float s_w = 0.f, s_mag = 0.f, s_dir = 0.f;
    #pragma unroll
    for (int i = 0; i < 4; ++i) {
        float gxo = to_[i + 2] - to_[i];
        float gyo = fmaf(2.f, uo[i + 1], uo[i] + uo[i + 2]);
        float gxt = tt_[i + 2] - tt_[i];
        float gyt = fmaf(2.f, ut[i + 1], ut[i] + ut[i + 2]);

        float mago = __builtin_amdgcn_sqrtf(fmaf(gxo, gxo, fmaf(gyo, gyo, 1e-8f)));
        float magt = __builtin_amdgcn_sqrtf(fmaf(gxt, gxt, fmaf(gyt, gyt, 1e-8f)));

        float cross = gyo * gxt - gxo * gyt;
        float dotp  = fmaf(gxo, gxt, gyo * gyt);
        float dd = abs_atan2_fast(cross, dotp);

        s_w   += wgt[i];
        s_mag += wgt[i] * fabsf(mago - magt);
        s_dir += dd * wgt[i];
    }

    // ---- block reduction ----
    #pragma unroll
    for (int o = 32; o > 0; o >>= 1) {
        s_w   += __shfl_down(s_w,   o, 64);
        s_mag += __shfl_down(s_mag, o, 64);
        s_dir += __shfl_down(s_dir, o, 64);
    }
    const int wid = tid >> 6;
    if ((tid & 63) == 0) { red[0][wid] = s_w; red[1][wid] = s_mag; red[2][wid] = s_dir; }
    __syncthreads();
    if (tid == 0) {
        const int bid = ((int)blockIdx.z * gridDim.y + blockIdx.y) * gridDim.x + blockIdx.x;
        partials[bid]            = red[0][0] + red[0][1] + red[0][2] + red[0][3];
        partials[NBLK + bid]     = red[1][0] + red[1][1] + red[1][2] + red[1][3];
        partials[2 * NBLK + bid] = red[2][0] + red[2][1] + red[2][2] + red[2][3];
    }
}

__global__ __launch_bounds__(256) void egcl_finalize(
    const float* __restrict__ partials, float* __restrict__ out)
{
    __shared__ double red[3][4];
    const int tid = threadIdx.x;
    double s0 = 0.0, s1 = 0.0, s2 = 0.0;
    const float4* p0 = (const float4*)partials;
    const float4* p1 = (const float4*)(partials + NBLK);
    const float4* p2 = (const float4*)(partials + 2 * NBLK);
    for (int i = tid; i < NBLK / 4; i += 256) {
        float4 a = p0[i], b = p1[i], c = p2[i];
        s0 += (double)a.x + (double)a.y + (double)a.z + (double)a.w;
        s1 += (double)b.x + (double)b.y + (double)b.z + (double)b.w;
        s2 += (double)c.x + (double)c.y + (double)c.z + (double)c.w;
    }
    #pragma unroll
    for (int o = 32; o > 0; o >>= 1) {
        s0 += __shfl_down(s0, o, 64);
        s1 += __shfl_down(s1, o, 64);
        s2 += __shfl_down(s2, o, 64);
    }
    const int wid = tid >> 6;
    if ((tid & 63) == 0) { red[0][wid] = s0; red[1][wid] = s1; red[2][wid] = s2; }
    __syncthreads();
    if (tid == 0) {
        double Sw   = red[0][0] + red[0][1] + red[0][2] + red[0][3];
        double Smag = red[1][0] + red[1][1] + red[1][2] + red[1][3];
        double Sdir = red[2][0] + red[2][1] + red[2][2] + red[2][3];
        const double N = (double)NBC * HH * WW;
        double mag_loss = Smag / N;
        if (Sw > 0.0) mag_loss = mag_loss / (Sw / N + 1e-8);
        double dir_loss = Sdir;
        if (Sw > 0.0) dir_loss = Sdir / (Sw + 1e-8);
        out[0] = (float)(mag_loss + dir_loss);
    }
}

extern "C" void kernel_launch(void* const* d_in, const int* in_sizes, int n_in,
                              void* d_out, int out_size, void* d_ws, size_t ws_size,
                              hipStream_t stream)
{
    const float* outp = (const float*)d_in[0];
    const float* tgtp = (const float*)d_in[1];
    const int*   maskp = (const int*)d_in[2];
    float* partials = (float*)d_ws;

    dim3 grid(WW / TW, HH / TH, NBC);
    egcl_fused<<<grid, 256, 0, stream>>>(outp, tgtp, maskp, partials);
    egcl_finalize<<<1, 256, 0, stream>>>(partials, (float*)d_out);
}

// Round 7
// 37.365 us; speedup vs baseline: 6.8206x; 1.2468x over previous
//
#include <hip/hip_runtime.h>
#include <math.h>

#define HH 512
#define WW 512
#define NBC 24          // B*C = 8*3
#define TH 64
#define TW 32
#define RAD 4
#define NXT (WW / TW)                 // 16 x-tiles
#define NYT (HH / TH)                 // 8 y-tiles
#define NBLK (NXT * NYT * NBC)        // 3072
#define PI_F 3.14159265358979323846f
#define SMW 36          // LDS row stride (floats), multiple of 4 for aligned float4

// Gaussian taps: exp(-0.5*x^2)/sum, x=-4..4 (double-computed, f32-rounded;
// <=1 ulp vs jnp's f32 path).
__device__ __constant__ float GW[9] = {
    1.3383023e-04f, 4.4318484e-03f, 5.3990968e-02f, 2.4197073e-01f,
    3.9894228e-01f, 2.4197073e-01f, 5.3990968e-02f, 4.4318484e-03f,
    1.3383023e-04f
};

// |atan2(y,x)| in [0,pi], branchless, ~3e-7 max error, NaN-free.
__device__ __forceinline__ float abs_atan2_fast(float y, float x)
{
    float ax = fabsf(x), ay = fabsf(y);
    float mx = fmaxf(ax, ay), mn = fminf(ax, ay);
    float t = mn * __builtin_amdgcn_rcpf(fmaxf(mx, 1e-30f));
    float s = t * t;
    float r = -0.01172120f;
    r = fmaf(r, s, 0.05265332f);
    r = fmaf(r, s, -0.11643287f);
    r = fmaf(r, s, 0.19354346f);
    r = fmaf(r, s, -0.33262347f);
    r = fmaf(r, s, 0.99997726f);
    r = r * t;                                  // atan(mn/mx) in [0, pi/4]
    r = (ay > ax) ? (0.5f * PI_F - r) : r;      // undo octant swap
    r = (x < 0.f) ? (PI_F - r) : r;             // quadrant
    return r;
}

__global__ __launch_bounds__(256) void egcl_fused(
    const float* __restrict__ outp,
    const float* __restrict__ tgtp,
    const int*   __restrict__ maskp,
    float*       __restrict__ partials)  // [3][NBLK]: w, mag, dir
{
    __shared__ __align__(16) float smh[TH + 8][SMW];  // 72 rows H-blurred mask (cols 0..31)
    __shared__ __align__(16) float oT[TH + 2][SMW];   // 66 rows, cols 0..35 = image x0-1..x0+34
    __shared__ __align__(16) float tT[TH + 2][SMW];
    __shared__ float red[3][4];

    const int tid = threadIdx.x;

    // XCD-aware bijective swizzle: each XCD gets 3 contiguous z-planes
    const int bid = (int)blockIdx.x;
    const int nb  = (bid & 7) * (NBLK / 8) + (bid >> 3);
    const int xt  = nb & 15;            // x-tile (fastest -> row-of-tiles locality)
    const int yt  = (nb >> 4) & 7;
    const int z   = nb >> 7;
    const int y0  = yt * TH;
    const int x0  = xt * TW;
    const size_t plane = (size_t)z * (HH * WW);
    const bool xedge = (x0 == 0) || (x0 == WW - TW);

    // ---- mask: global -> registers -> H-blur -> smh. 72 rows x 8 groups = 576 tasks ----
    for (int i = tid; i < (TH + 8) * 8; i += 256) {
        int r = i >> 3, cg = (i & 7) << 2;
        int gy = y0 + r - RAD;
        gy = (gy < 0) ? (-gy - 1) : ((gy >= HH) ? (2 * HH - 1 - gy) : gy);
        const int* mrow = maskp + plane + (size_t)gy * WW;
        float win[12];
        if (!xedge) {
            int4 a = *(const int4*)&mrow[x0 + cg - 4];
            int4 b = *(const int4*)&mrow[x0 + cg];
            int4 c = *(const int4*)&mrow[x0 + cg + 4];
            win[0] = (float)a.x; win[1]  = (float)a.y; win[2]  = (float)a.z; win[3]  = (float)a.w;
            win[4] = (float)b.x; win[5]  = (float)b.y; win[6]  = (float)b.z; win[7]  = (float)b.w;
            win[8] = (float)c.x; win[9]  = (float)c.y; win[10] = (float)c.z; win[11] = (float)c.w;
        } else {
            #pragma unroll
            for (int k = 0; k < 12; ++k) {
                int gx = x0 + cg - 4 + k;
                gx = (gx < 0) ? (-gx - 1) : ((gx >= WW) ? (2 * WW - 1 - gx) : gx);
                win[k] = (float)mrow[gx];
            }
        }
        float s0 = 0.f, s1 = 0.f, s2 = 0.f, s3 = 0.f;
        #pragma unroll
        for (int j = 0; j < 9; ++j) {
            float gw = GW[j];
            s0 = fmaf(gw, win[j],     s0);
            s1 = fmaf(gw, win[j + 1], s1);
            s2 = fmaf(gw, win[j + 2], s2);
            s3 = fmaf(gw, win[j + 3], s3);
        }
        *(float4*)&smh[r][cg] = make_float4(s0, s1, s2, s3);
    }

    // ---- o/t tiles: 66 rows x 9 groups of 4 = 594 tasks ----
    for (int i = tid; i < (TH + 2) * 9; i += 256) {
        int r = i / 9, g = i - r * 9;
        int gy = y0 + r - 1;
        bool rowin = (gy >= 0) && (gy < HH);
        float4 vo = make_float4(0.f, 0.f, 0.f, 0.f);
        float4 vt = vo;
        if (rowin) {
            const size_t rowbase = plane + (size_t)gy * WW;
            if (!xedge) {
                vo = *(const float4*)&outp[rowbase + (x0 - 1 + 4 * g)];
                vt = *(const float4*)&tgtp[rowbase + (x0 - 1 + 4 * g)];
            } else {
                float a[4], b[4];
                #pragma unroll
                for (int k = 0; k < 4; ++k) {
                    int gx = x0 - 1 + 4 * g + k;
                    bool in = (gx >= 0) && (gx < WW);
                    size_t idx = rowbase + (in ? gx : 0);
                    a[k] = in ? outp[idx] : 0.f;
                    b[k] = in ? tgtp[idx] : 0.f;
                }
                vo = make_float4(a[0], a[1], a[2], a[3]);
                vt = make_float4(b[0], b[1], b[2], b[3]);
            }
        }
        *(float4*)&oT[r][4 * g] = vo;
        *(float4*)&tT[r][4 * g] = vt;
    }
    __syncthreads();   // the ONLY barrier

    // ---- compute: thread owns a 2-row x 4-col patch ----
    const int tr  = tid >> 3;           // 0..31
    const int c4  = (tid & 7) << 2;     // 0..28
    const int pr0 = tr << 1;            // output rows pr0, pr0+1

    // V-blur over 10 smh rows -> weights for both rows
    float4 a0 = make_float4(0.f, 0.f, 0.f, 0.f);
    float4 a1 = a0;
    #pragma unroll
    for (int j = 0; j < 10; ++j) {
        float4 m = *(const float4*)&smh[pr0 + j][c4];
        if (j < 9) {
            float gw = GW[j];
            a0.x = fmaf(gw, m.x, a0.x); a0.y = fmaf(gw, m.y, a0.y);
            a0.z = fmaf(gw, m.z, a0.z); a0.w = fmaf(gw, m.w, a0.w);
        }
        if (j > 0) {
            float gw = GW[j - 1];
            a1.x = fmaf(gw, m.x, a1.x); a1.y = fmaf(gw, m.y, a1.y);
            a1.z = fmaf(gw, m.z, a1.z); a1.w = fmaf(gw, m.w, a1.w);
        }
    }
    float wgt[2][4];
    {
        float smv[2][4] = {{a0.x, a0.y, a0.z, a0.w}, {a1.x, a1.y, a1.z, a1.w}};
        #pragma unroll
        for (int p = 0; p < 2; ++p)
            #pragma unroll
            for (int i = 0; i < 4; ++i) {
                float sm = fminf(fmaxf(smv[p][i], 0.f), 1.f);
                float w = 1.f - fabsf(sm - 0.5f) * 2.f;
                wgt[p][i] = fminf(fmaxf(w, 0.f), 1.f);
            }
    }

    // Sobel: 4 LDS rows x 6 cols per image
    float Ro[4][6], Rt[4][6];
    #pragma unroll
    for (int j = 0; j < 4; ++j) {
        *(float4*)&Ro[j][0] = *(const float4*)&oT[pr0 + j][c4];
        *(float2*)&Ro[j][4] = *(const float2*)&oT[pr0 + j][c4 + 4];
        *(float4*)&Rt[j][0] = *(const float4*)&tT[pr0 + j][c4];
        *(float2*)&Rt[j][4] = *(const float2*)&tT[pr0 + j][c4 + 4];
    }

    // separable Sobel for a 2-row pair: t = a+2b+c (gx = t[i+2]-t[i]),
    // u = c-a (gy = u[i]+2u[i+1]+u[i+2])
    float gxo[2][4], gyo[2][4], gxt[2][4], gyt[2][4];
    {
        float t0[6], t1[6], u0[6], u1[6];
        #pragma unroll
        for (int j = 0; j < 6; ++j) {
            t0[j] = fmaf(2.f, Ro[1][j], Ro[0][j] + Ro[2][j]);
            t1[j] = fmaf(2.f, Ro[2][j], Ro[1][j] + Ro[3][j]);
            u0[j] = Ro[2][j] - Ro[0][j];
            u1[j] = Ro[3][j] - Ro[1][j];
        }
        #pragma unroll
        for (int i = 0; i < 4; ++i) {
            gxo[0][i] = t0[i + 2] - t0[i];
            gxo[1][i] = t1[i + 2] - t1[i];
            gyo[0][i] = fmaf(2.f, u0[i + 1], u0[i] + u0[i + 2]);
            gyo[1][i] = fmaf(2.f, u1[i + 1], u1[i] + u1[i + 2]);
        }
        #pragma unroll
        for (int j = 0; j < 6; ++j) {
            t0[j] = fmaf(2.f, Rt[1][j], Rt[0][j] + Rt[2][j]);
            t1[j] = fmaf(2.f, Rt[2][j], Rt[1][j] + Rt[3][j]);
            u0[j] = Rt[2][j] - Rt[0][j];
            u1[j] = Rt[3][j] - Rt[1][j];
        }
        #pragma unroll
        for (int i = 0; i < 4; ++i) {
            gxt[0][i] = t0[i + 2] - t0[i];
            gxt[1][i] = t1[i + 2] - t1[i];
            gyt[0][i] = fmaf(2.f, u0[i + 1], u0[i] + u0[i + 2]);
            gyt[1][i] = fmaf(2.f, u1[i + 1], u1[i] + u1[i + 2]);
        }
    }

    float s_w = 0.f, s_mag = 0.f, s_dir = 0.f;
    #pragma unroll
    for (int p = 0; p < 2; ++p) {
        #pragma unroll
        for (int i = 0; i < 4; ++i) {
            float xo = gxo[p][i], yo = gyo[p][i];
            float xt_ = gxt[p][i], yt_ = gyt[p][i];
            float mago = __builtin_amdgcn_sqrtf(fmaf(xo, xo, fmaf(yo, yo, 1e-8f)));
            float magt = __builtin_amdgcn_sqrtf(fmaf(xt_, xt_, fmaf(yt_, yt_, 1e-8f)));
            float cross = yo * xt_ - xo * yt_;
            float dotp  = fmaf(xo, xt_, yo * yt_);
            float dd = abs_atan2_fast(cross, dotp);
            float w = wgt[p][i];
            s_w   += w;
            s_mag += w * fabsf(mago - magt);
            s_dir += dd * w;
        }
    }

    // ---- block reduction ----
    #pragma unroll
    for (int o = 32; o > 0; o >>= 1) {
        s_w   += __shfl_down(s_w,   o, 64);
        s_mag += __shfl_down(s_mag, o, 64);
        s_dir += __shfl_down(s_dir, o, 64);
    }
    const int wid = tid >> 6;
    if ((tid & 63) == 0) { red[0][wid] = s_w; red[1][wid] = s_mag; red[2][wid] = s_dir; }
    __syncthreads();
    if (tid == 0) {
        partials[bid]            = red[0][0] + red[0][1] + red[0][2] + red[0][3];
        partials[NBLK + bid]     = red[1][0] + red[1][1] + red[1][2] + red[1][3];
        partials[2 * NBLK + bid] = red[2][0] + red[2][1] + red[2][2] + red[2][3];
    }
}

__global__ __launch_bounds__(256) void egcl_finalize(
    const float* __restrict__ partials, float* __restrict__ out)
{
    __shared__ double red[3][4];
    const int tid = threadIdx.x;
    double s0 = 0.0, s1 = 0.0, s2 = 0.0;
    const float4* p0 = (const float4*)partials;
    const float4* p1 = (const float4*)(partials + NBLK);
    const float4* p2 = (const float4*)(partials + 2 * NBLK);
    for (int i = tid; i < NBLK / 4; i += 256) {
        float4 a = p0[i], b = p1[i], c = p2[i];
        s0 += (double)a.x + (double)a.y + (double)a.z + (double)a.w;
        s1 += (double)b.x + (double)b.y + (double)b.z + (double)b.w;
        s2 += (double)c.x + (double)c.y + (double)c.z + (double)c.w;
    }
    #pragma unroll
    for (int o = 32; o > 0; o >>= 1) {
        s0 += __shfl_down(s0, o, 64);
        s1 += __shfl_down(s1, o, 64);
        s2 += __shfl_down(s2, o, 64);
    }
    const int wid = tid >> 6;
    if ((tid & 63) == 0) { red[0][wid] = s0; red[1][wid] = s1; red[2][wid] = s2; }
    __syncthreads();
    if (tid == 0) {
        double Sw   = red[0][0] + red[0][1] + red[0][2] + red[0][3];
        double Smag = red[1][0] + red[1][1] + red[1][2] + red[1][3];
        double Sdir = red[2][0] + red[2][1] + red[2][2] + red[2][3];
        const double N = (double)NBC * HH * WW;
        double mag_loss = Smag / N;
        if (Sw > 0.0) mag_loss = mag_loss / (Sw / N + 1e-8);
        double dir_loss = Sdir;
        if (Sw > 0.0) dir_loss = Sdir / (Sw + 1e-8);
        out[0] = (float)(mag_loss + dir_loss);
    }
}

extern "C" void kernel_launch(void* const* d_in, const int* in_sizes, int n_in,
                              void* d_out, int out_size, void* d_ws, size_t ws_size,
                              hipStream_t stream)
{
    const float* outp = (const float*)d_in[0];
    const float* tgtp = (const float*)d_in[1];
    const int*   maskp = (const int*)d_in[2];
    float* partials = (float*)d_ws;

    egcl_fused<<<dim3(NBLK, 1, 1), 256, 0, stream>>>(outp, tgtp, maskp, partials);
    egcl_finalize<<<1, 256, 0, stream>>>(partials, (float*)d_out);
}